// Round 4
// baseline (427.173 us; speedup 1.0000x reference)
//
#include <hip/hip_runtime.h>

// Problem constants (B=4, L=4096, E=512, H=16, D=32)
#define EMBED  512
#define NHEAD  16
#define HDIM   32
#define NBATCH 4
#define SEQ    4096
#define NROWS  (NBATCH * SEQ)   // 16384
#define NE     (NROWS * EMBED)  // 8388608 elements per activation tensor
#define WN     (EMBED * EMBED)  // 262144 elements per weight
#define FEPS   1e-6f

typedef __attribute__((ext_vector_type(8))) short short8;
typedef __attribute__((ext_vector_type(4))) float f32x4;

// ---- bf16 split helpers (RNE) ----
__device__ __forceinline__ short f2bf(float x) {
    unsigned u = __float_as_uint(x);
    u += 0x7FFFu + ((u >> 16) & 1u);
    return (short)(u >> 16);
}
__device__ __forceinline__ float bf2f(short h) {
    return __uint_as_float(((unsigned)(unsigned short)h) << 16);
}

// ---- convert everything fp32 -> split bf16 + zero KV/Ksum, one pass ------
__global__ __launch_bounds__(256)
void convert_all(const float* __restrict__ q, const float* __restrict__ k,
                 const float* __restrict__ v,
                 const float* __restrict__ wq, const float* __restrict__ wk,
                 const float* __restrict__ wv, const float* __restrict__ wm,
                 short* __restrict__ qh, short* __restrict__ ql,
                 short* __restrict__ kh, short* __restrict__ kl,
                 short* __restrict__ vh, short* __restrict__ vl,
                 short* __restrict__ wqh, short* __restrict__ wql,
                 short* __restrict__ wkh, short* __restrict__ wkl,
                 short* __restrict__ wvh, short* __restrict__ wvl,
                 short* __restrict__ wmh, short* __restrict__ wml,
                 float* __restrict__ zeroDst) {
    const int b = blockIdx.x;
    if (b >= 12800) {                    // fused memset: KVb + KSb = 67584 f32
        const int nvec = (64 * 1024 + 64 * HDIM) / 4;   // 16896 float4
        float4 z = {0.f, 0.f, 0.f, 0.f};
        for (int i = (b - 12800) * 256 + threadIdx.x; i < nvec; i += 16 * 256)
            ((float4*)zeroDst)[i] = z;
        return;
    }
    const float* src; short* dh; short* dl; int boff;
    if (b < 12288) {
        const int s = b >> 12;
        src = (s == 0) ? q  : (s == 1) ? k  : v;
        dh  = (s == 0) ? qh : (s == 1) ? kh : vh;
        dl  = (s == 0) ? ql : (s == 1) ? kl : vl;
        boff = b & 4095;
    } else {
        const int s = (b - 12288) >> 7;
        src = (s == 0) ? wq  : (s == 1) ? wk  : (s == 2) ? wv  : wm;
        dh  = (s == 0) ? wqh : (s == 1) ? wkh : (s == 2) ? wvh : wmh;
        dl  = (s == 0) ? wql : (s == 1) ? wkl : (s == 2) ? wvl : wml;
        boff = (b - 12288) & 127;
    }
    const size_t i = ((size_t)boff * 256 + threadIdx.x) * 8;
    float4 x0 = *(const float4*)(src + i);
    float4 x1 = *(const float4*)(src + i + 4);
    float vv[8] = {x0.x, x0.y, x0.z, x0.w, x1.x, x1.y, x1.z, x1.w};
    short8 h, l;
#pragma unroll
    for (int t = 0; t < 8; ++t) {
        short hb = f2bf(vv[t]);
        h[t] = hb;
        l[t] = f2bf(vv[t] - bf2f(hb));
    }
    *(short8*)(dh + i) = h;
    *(short8*)(dl + i) = l;
}

// ---- direct-fragment GEMM core: NO LDS, NO barriers ----------------------
// 128x128 tile, 4 waves (2M x 2N), per-wave 64x64 (4x4 frags). Both A and B
// are k-contiguous in memory, exactly the MFMA fragment layout: lane(l15,kg)
// reads row (w*+i*16+l15), 16B at k-offset kg*8 -> a wave covers 16 full 64B
// cache lines, fully coalesced. 2-deep register pipeline (named sets, static
// indexing); latency hidden by pipeline + 2 blocks/CU. L2 reuse: weights
// resident, A-panels streamed once per XCD (chunked swizzle, bn inner).
__device__ __forceinline__ void ldfrag(
    const short* __restrict__ pa, const short* __restrict__ pal,
    const short* __restrict__ pb, const short* __restrict__ pbl, int ko,
    short8 ah[4], short8 al[4], short8 bh[4], short8 bl[4])
{
#pragma unroll
    for (int i = 0; i < 4; ++i) {
        ah[i] = *(const short8*)(pa  + (size_t)i * 16 * EMBED + ko);
        al[i] = *(const short8*)(pal + (size_t)i * 16 * EMBED + ko);
        bh[i] = *(const short8*)(pb  + (size_t)i * 16 * EMBED + ko);
        bl[i] = *(const short8*)(pbl + (size_t)i * 16 * EMBED + ko);
    }
}

__device__ __forceinline__ void mfma48(
    const short8 ah[4], const short8 al[4],
    const short8 bh[4], const short8 bl[4], f32x4 acc[4][4])
{
#pragma unroll
    for (int i = 0; i < 4; ++i)
#pragma unroll
        for (int j = 0; j < 4; ++j) {
            acc[i][j] = __builtin_amdgcn_mfma_f32_16x16x32_bf16(ah[i], bh[j], acc[i][j], 0, 0, 0);
            acc[i][j] = __builtin_amdgcn_mfma_f32_16x16x32_bf16(ah[i], bl[j], acc[i][j], 0, 0, 0);
            acc[i][j] = __builtin_amdgcn_mfma_f32_16x16x32_bf16(al[i], bh[j], acc[i][j], 0, 0, 0);
        }
}

__device__ __forceinline__ void gemm_direct(
    const short* __restrict__ Ah, const short* __restrict__ Al,
    const short* __restrict__ Bh, const short* __restrict__ Bl,
    int bm, int bn, f32x4 acc[4][4])
{
    const int lane = threadIdx.x & 63;
    const int wave = threadIdx.x >> 6;
    const int l15  = lane & 15;
    const int kg   = lane >> 4;
    const int wm   = (wave >> 1) * 64;
    const int wn   = (wave & 1) * 64;

    const short* pa  = Ah + (size_t)(bm + wm + l15) * EMBED + kg * 8;
    const short* pal = Al + (size_t)(bm + wm + l15) * EMBED + kg * 8;
    const short* pb  = Bh + (size_t)(bn + wn + l15) * EMBED + kg * 8;
    const short* pbl = Bl + (size_t)(bn + wn + l15) * EMBED + kg * 8;

    short8 A0h[4], A0l[4], B0h[4], B0l[4];
    short8 A1h[4], A1l[4], B1h[4], B1l[4];

    ldfrag(pa, pal, pb, pbl, 0, A0h, A0l, B0h, B0l);
#pragma unroll 1
    for (int k0 = 0; k0 < EMBED - 64; k0 += 64) {
        ldfrag(pa, pal, pb, pbl, k0 + 32, A1h, A1l, B1h, B1l);
        mfma48(A0h, A0l, B0h, B0l, acc);
        ldfrag(pa, pal, pb, pbl, k0 + 64, A0h, A0l, B0h, B0l);
        mfma48(A1h, A1l, B1h, B1l, acc);
    }
    ldfrag(pa, pal, pb, pbl, EMBED - 32, A1h, A1l, B1h, B1l);
    mfma48(A0h, A0l, B0h, B0l, acc);
    mfma48(A1h, A1l, B1h, B1l, acc);
}

// ---- fused QKV projection GEMM (direct): Q->fp32, K/V->split bf16 planes -
__global__ __launch_bounds__(256, 2)
void qkv_gemm(const short* __restrict__ Aqh, const short* __restrict__ Aql,
              const short* __restrict__ Akh, const short* __restrict__ Akl,
              const short* __restrict__ Avh, const short* __restrict__ Avl,
              const short* __restrict__ WqH, const short* __restrict__ WqL,
              const short* __restrict__ WkH, const short* __restrict__ WkL,
              const short* __restrict__ WvH, const short* __restrict__ WvL,
              float* __restrict__ Qb,
              short* __restrict__ KhP, short* __restrict__ KlP,
              short* __restrict__ VhP, short* __restrict__ VlP) {
    // chunked XCD swizzle: xcd owns 16 bm-panels per op; bn inner so the
    // A-panel is reused from L2 across its 4 bn-blocks; weights L2-resident.
    const int lin = blockIdx.x;
    const int xcd = lin & 7;
    const int w   = lin >> 3;            // 0..191
    const int op  = w >> 6;              // 0=q,1=k,2=v
    const int r   = w & 63;
    const int bn  = (r & 3) * 128;
    const int bm  = ((xcd << 4) + (r >> 2)) * 128;

    const short* Ah = (op == 0) ? Aqh : (op == 1) ? Akh : Avh;
    const short* Al = (op == 0) ? Aql : (op == 1) ? Akl : Avl;
    const short* Bh = (op == 0) ? WqH : (op == 1) ? WkH : WvH;
    const short* Bl = (op == 0) ? WqL : (op == 1) ? WkL : WvL;

    f32x4 acc[4][4];
#pragma unroll
    for (int i = 0; i < 4; ++i)
#pragma unroll
        for (int j = 0; j < 4; ++j) acc[i][j] = (f32x4)0.0f;

    gemm_direct(Ah, Al, Bh, Bl, bm, bn, acc);

    const int lane = threadIdx.x & 63;
    const int wave = threadIdx.x >> 6;
    const int l15  = lane & 15;
    const int kg   = lane >> 4;
    const int wm   = (wave >> 1) * 64;
    const int wn   = (wave & 1) * 64;

    if (op == 0) {                       // Q: elu+1, fp32 (message needs it)
#pragma unroll
        for (int i = 0; i < 4; ++i)
#pragma unroll
            for (int j = 0; j < 4; ++j) {
                const int col = bn + wn + j * 16 + l15;
#pragma unroll
                for (int rr = 0; rr < 4; ++rr) {
                    const int row = bm + wm + i * 16 + kg * 4 + rr;
                    float vv = acc[i][j][rr];
                    vv = (vv > 0.f) ? (vv + 1.f) : __expf(vv);
                    Qb[(size_t)row * EMBED + col] = vv;
                }
            }
    } else {                             // K: elu+1; V: /SEQ; split bf16 out
        short* Hp = (op == 1) ? KhP : VhP;
        short* Lp = (op == 1) ? KlP : VlP;
#pragma unroll
        for (int i = 0; i < 4; ++i)
#pragma unroll
            for (int j = 0; j < 4; ++j) {
                const int col = bn + wn + j * 16 + l15;
#pragma unroll
                for (int rr = 0; rr < 4; ++rr) {
                    const int row = bm + wm + i * 16 + kg * 4 + rr;
                    float vv = acc[i][j][rr];
                    if (op == 1) vv = (vv > 0.f) ? (vv + 1.f) : __expf(vv);
                    else         vv = vv * (1.0f / (float)SEQ);
                    short hb = f2bf(vv);
                    Hp[(size_t)row * EMBED + col] = hb;
                    Lp[(size_t)row * EMBED + col] = f2bf(vv - bf2f(hb));
                }
            }
    }
}

// ---- merge GEMM (direct): A = message planes, B = Wm planes --------------
__global__ __launch_bounds__(256, 2)
void merge_gemm(const short* __restrict__ Mh, const short* __restrict__ Ml,
                const short* __restrict__ WhP, const short* __restrict__ WlP,
                float* __restrict__ C) {
    const int lin = blockIdx.x;
    const int xcd = lin & 7;
    const int w   = lin >> 3;            // 0..63
    const int bn  = (w & 3) * 128;
    const int bm  = ((xcd << 4) + (w >> 2)) * 128;

    f32x4 acc[4][4];
#pragma unroll
    for (int i = 0; i < 4; ++i)
#pragma unroll
        for (int j = 0; j < 4; ++j) acc[i][j] = (f32x4)0.0f;

    gemm_direct(Mh, Ml, WhP, WlP, bm, bn, acc);

    const int lane = threadIdx.x & 63;
    const int wave = threadIdx.x >> 6;
    const int l15  = lane & 15;
    const int kg   = lane >> 4;
    const int wm   = (wave >> 1) * 64;
    const int wn   = (wave & 1) * 64;
#pragma unroll
    for (int i = 0; i < 4; ++i)
#pragma unroll
        for (int j = 0; j < 4; ++j) {
            const int col = bn + wn + j * 16 + l15;
#pragma unroll
            for (int rr = 0; rr < 4; ++rr) {
                const int row = bm + wm + i * 16 + kg * 4 + rr;
                C[(size_t)row * EMBED + col] = acc[i][j][rr];
            }
        }
}

// ---- KV + Ksum MFMA: inputs pre-split planes (no conversion VALU) --------
__global__ __launch_bounds__(256)
void kv_ksum_mfma(const short* __restrict__ KhP, const short* __restrict__ KlP,
                  const short* __restrict__ VhP, const short* __restrict__ VlP,
                  float* __restrict__ KV, float* __restrict__ Ksum) {
    __shared__ char smem[34816];
    short (*Kh)[34] = (short (*)[34])smem;
    short (*Kl)[34] = (short (*)[34])(smem + 8704);
    short (*Vh)[34] = (short (*)[34])(smem + 17408);
    short (*Vl)[34] = (short (*)[34])(smem + 26112);

    const int bh_ = blockIdx.y;
    const int b = bh_ >> 4, h = bh_ & 15;
    const int s0 = blockIdx.x * 256;
    const int t = threadIdx.x;
    const int lane = t & 63, wave = t >> 6;
    const int l15 = lane & 15, kg = lane >> 4;
    const int ws = wave * 32;

    const int sl = t >> 1;
    const int dsel = (t & 1) * 16;
    const size_t rbase = (size_t)(b * SEQ + s0 + sl) * EMBED + h * HDIM + dsel;

    f32x4 kvacc[2][2], ksacc[2];
#pragma unroll
    for (int i = 0; i < 2; ++i) {
        ksacc[i] = (f32x4)0.0f;
#pragma unroll
        for (int j = 0; j < 2; ++j) kvacc[i][j] = (f32x4)0.0f;
    }
    short8 ones;
#pragma unroll
    for (int q = 0; q < 8; ++q) ones[q] = (short)0x3F80;   // bf16 1.0

    short8 pk[4], pv[4];   // {kh0,kh1,kl0,kl1}, {vh0,vh1,vl0,vl1}
    pk[0] = *(const short8*)(KhP + rbase);
    pk[1] = *(const short8*)(KhP + rbase + 8);
    pk[2] = *(const short8*)(KlP + rbase);
    pk[3] = *(const short8*)(KlP + rbase + 8);
    pv[0] = *(const short8*)(VhP + rbase);
    pv[1] = *(const short8*)(VhP + rbase + 8);
    pv[2] = *(const short8*)(VlP + rbase);
    pv[3] = *(const short8*)(VlP + rbase + 8);

#pragma unroll 1
    for (int it = 0; it < 2; ++it) {
        __syncthreads();
        *(short8*)&Kh[sl][dsel]     = pk[0];
        *(short8*)&Kh[sl][dsel + 8] = pk[1];
        *(short8*)&Kl[sl][dsel]     = pk[2];
        *(short8*)&Kl[sl][dsel + 8] = pk[3];
        *(short8*)&Vh[sl][dsel]     = pv[0];
        *(short8*)&Vh[sl][dsel + 8] = pv[1];
        *(short8*)&Vl[sl][dsel]     = pv[2];
        *(short8*)&Vl[sl][dsel + 8] = pv[3];
        __syncthreads();
        if (it == 0) {
            const size_t rb2 = rbase + (size_t)128 * EMBED;
            pk[0] = *(const short8*)(KhP + rb2);
            pk[1] = *(const short8*)(KhP + rb2 + 8);
            pk[2] = *(const short8*)(KlP + rb2);
            pk[3] = *(const short8*)(KlP + rb2 + 8);
            pv[0] = *(const short8*)(VhP + rb2);
            pv[1] = *(const short8*)(VhP + rb2 + 8);
            pv[2] = *(const short8*)(VlP + rb2);
            pv[3] = *(const short8*)(VlP + rb2 + 8);
        }
        short8 kah[2], kal[2], vbh[2], vbl[2];
#pragma unroll
        for (int i = 0; i < 2; ++i) {
#pragma unroll
            for (int q = 0; q < 8; ++q) {
                const int srow = ws + kg * 8 + q;
                const int col  = i * 16 + l15;
                kah[i][q] = Kh[srow][col];
                kal[i][q] = Kl[srow][col];
                vbh[i][q] = Vh[srow][col];
                vbl[i][q] = Vl[srow][col];
            }
        }
#pragma unroll
        for (int i = 0; i < 2; ++i) {
#pragma unroll
            for (int j = 0; j < 2; ++j) {
                kvacc[i][j] = __builtin_amdgcn_mfma_f32_16x16x32_bf16(kah[i], vbh[j], kvacc[i][j], 0, 0, 0);
                kvacc[i][j] = __builtin_amdgcn_mfma_f32_16x16x32_bf16(kah[i], vbl[j], kvacc[i][j], 0, 0, 0);
                kvacc[i][j] = __builtin_amdgcn_mfma_f32_16x16x32_bf16(kal[i], vbh[j], kvacc[i][j], 0, 0, 0);
            }
            ksacc[i] = __builtin_amdgcn_mfma_f32_16x16x32_bf16(kah[i], ones, ksacc[i], 0, 0, 0);
            ksacc[i] = __builtin_amdgcn_mfma_f32_16x16x32_bf16(kal[i], ones, ksacc[i], 0, 0, 0);
        }
    }

    __syncthreads();
    float* red = (float*)smem;
    float* myred = red + wave * 1056;
#pragma unroll
    for (int i = 0; i < 2; ++i)
#pragma unroll
        for (int j = 0; j < 2; ++j)
#pragma unroll
            for (int r = 0; r < 4; ++r)
                myred[(i * 16 + kg * 4 + r) * 32 + j * 16 + l15] = kvacc[i][j][r];
    if (l15 == 0) {
#pragma unroll
        for (int i = 0; i < 2; ++i)
#pragma unroll
            for (int r = 0; r < 4; ++r)
                myred[1024 + i * 16 + kg * 4 + r] = ksacc[i][r];
    }
    __syncthreads();
    float* kvout = KV + (size_t)bh_ * 1024;
    for (int idx = t; idx < 1024; idx += 256) {
        float s4 = red[idx] + red[1056 + idx] + red[2112 + idx] + red[3168 + idx];
        atomicAdd(&kvout[idx], s4);
    }
    if (t < 32) {
        float s4 = red[1024 + t] + red[1056 + 1024 + t] + red[2112 + 1024 + t] + red[3168 + 1024 + t];
        atomicAdd(&Ksum[bh_ * 32 + t], s4);
    }
}

// ---- message: M[l,h,:] = (SEQ/(Q.Ksum+eps)) * Q @ KV[b,h], emit split bf16
__global__ __launch_bounds__(512)
void message_kernel(const float* __restrict__ Q, const float* __restrict__ KV,
                    const float* __restrict__ Ksum,
                    short* __restrict__ Mh, short* __restrict__ Ml) {
    const int blk  = blockIdx.x;
    const int row0 = blk * 4;
    const int b    = row0 >> 12;
    const int t    = threadIdx.x;
    const int h    = t >> 5, e = t & 31;

    __shared__ float q[4][EMBED];
    __shared__ float ks[EMBED];
    ks[t] = Ksum[b * EMBED + t];
#pragma unroll
    for (int r = 0; r < 4; ++r) q[r][t] = Q[(size_t)(row0 + r) * EMBED + t];

    const float* kvh = KV + (size_t)(b * NHEAD + h) * HDIM * HDIM + e;
    float kc[HDIM];
#pragma unroll
    for (int d = 0; d < HDIM; ++d) kc[d] = kvh[d * HDIM];
    __syncthreads();

#pragma unroll
    for (int r = 0; r < 4; ++r) {
        float zden = FEPS, m = 0.f;
#pragma unroll
        for (int d = 0; d < HDIM; ++d) {
            float qd = q[r][h * HDIM + d];
            zden = fmaf(qd, ks[h * HDIM + d], zden);
            m    = fmaf(qd, kc[d], m);
        }
        float vv = m * ((float)SEQ / zden);
        short hb = f2bf(vv);
        Mh[(size_t)(row0 + r) * EMBED + t] = hb;
        Ml[(size_t)(row0 + r) * EMBED + t] = f2bf(vv - bf2f(hb));
    }
}

// ---- launch ----
extern "C" void kernel_launch(void* const* d_in, const int* in_sizes, int n_in,
                              void* d_out, int out_size, void* d_ws, size_t ws_size,
                              hipStream_t stream) {
    const float* query = (const float*)d_in[0];
    const float* key   = (const float*)d_in[1];
    const float* value = (const float*)d_in[2];
    const float* Wq    = (const float*)d_in[3];
    const float* Wk    = (const float*)d_in[4];
    const float* Wv    = (const float*)d_in[5];
    const float* Wm    = (const float*)d_in[6];
    float* out = (float*)d_out;

    float* ws  = (float*)d_ws;
    float* Qb  = ws;                              // NE fp32
    short* KhP = (short*)(Qb + (size_t)NE);       // 4 split planes, NE shorts each
    short* KlP = KhP + (size_t)NE;
    short* VhP = KhP + 2 * (size_t)NE;
    short* VlP = KhP + 3 * (size_t)NE;
    float* KVb = (float*)(KhP + 4 * (size_t)NE);  // 64*1024
    float* KSb = KVb + 64 * 1024;                 // 64*32
    short* wsp = (short*)(KSb + 64 * HDIM);
    short* WqH = wsp;            short* WqL = wsp + WN;
    short* WkH = wsp + 2 * WN;   short* WkL = wsp + 3 * WN;
    short* WvH = wsp + 4 * WN;   short* WvL = wsp + 5 * WN;
    short* WmH = wsp + 6 * WN;   short* WmL = wsp + 7 * WN;
    short* Xp  = wsp + 8 * WN;                    // 6 input planes, NE shorts each
    short* Qih = Xp;             short* Qil = Xp + (size_t)NE;
    short* Kih = Xp + 2 * (size_t)NE;  short* Kil = Xp + 3 * (size_t)NE;
    short* Vih = Xp + 4 * (size_t)NE;  short* Vil = Xp + 5 * (size_t)NE;
    // message planes alias Kih/Kil (dead after qkv_gemm)
    short* Mh = Kih;
    short* Ml = Kil;

    convert_all<<<12816, 256, 0, stream>>>(query, key, value, Wq, Wk, Wv, Wm,
                                           Qih, Qil, Kih, Kil, Vih, Vil,
                                           WqH, WqL, WkH, WkL,
                                           WvH, WvL, WmH, WmL, KVb);

    qkv_gemm<<<1536, 256, 0, stream>>>(Qih, Qil, Kih, Kil, Vih, Vil,
                                       WqH, WqL, WkH, WkL, WvH, WvL,
                                       Qb, KhP, KlP, VhP, VlP);

    kv_ksum_mfma<<<dim3(16, 64), 256, 0, stream>>>(KhP, KlP, VhP, VlP, KVb, KSb);
    message_kernel<<<NROWS / 4, 512, 0, stream>>>(Qb, KVb, KSb, Mh, Ml);

    merge_gemm<<<512, 256, 0, stream>>>(Mh, Ml, WmH, WmL, out);
}

// Round 5
// 306.723 us; speedup vs baseline: 1.3927x; 1.3927x over previous
//
#include <hip/hip_runtime.h>

// Problem constants (B=4, L=4096, E=512, H=16, D=32)
#define EMBED  512
#define NHEAD  16
#define HDIM   32
#define NBATCH 4
#define SEQ    4096
#define NROWS  (NBATCH * SEQ)   // 16384
#define NE     (NROWS * EMBED)  // 8388608 elements per activation tensor
#define WN     (EMBED * EMBED)  // 262144 elements per weight
#define FEPS   1e-6f

typedef __attribute__((ext_vector_type(8))) short short8;
typedef __attribute__((ext_vector_type(4))) float f32x4;

// ---- bf16 split helpers (RNE) ----
__device__ __forceinline__ short f2bf(float x) {
    unsigned u = __float_as_uint(x);
    u += 0x7FFFu + ((u >> 16) & 1u);
    return (short)(u >> 16);
}
__device__ __forceinline__ float bf2f(short h) {
    return __uint_as_float(((unsigned)(unsigned short)h) << 16);
}

// async global->LDS, 16B per lane, wave-uniform LDS base + lane*16
#define GLDS16(gp, lp)                                                   \
    __builtin_amdgcn_global_load_lds(                                    \
        (__attribute__((address_space(1))) void*)(void*)(gp),            \
        (__attribute__((address_space(3))) void*)(void*)(lp), 16, 0, 0)

// ---- convert everything fp32 -> split bf16 + zero KV/Ksum, one pass ------
__global__ __launch_bounds__(256)
void convert_all(const float* __restrict__ q, const float* __restrict__ k,
                 const float* __restrict__ v,
                 const float* __restrict__ wq, const float* __restrict__ wk,
                 const float* __restrict__ wv, const float* __restrict__ wm,
                 short* __restrict__ qh, short* __restrict__ ql,
                 short* __restrict__ kh, short* __restrict__ kl,
                 short* __restrict__ vh, short* __restrict__ vl,
                 short* __restrict__ wqh, short* __restrict__ wql,
                 short* __restrict__ wkh, short* __restrict__ wkl,
                 short* __restrict__ wvh, short* __restrict__ wvl,
                 short* __restrict__ wmh, short* __restrict__ wml,
                 float* __restrict__ zeroDst) {
    const int b = blockIdx.x;
    if (b >= 12800) {                    // fused memset: KVb + KSb = 67584 f32
        const int nvec = (64 * 1024 + 64 * HDIM) / 4;   // 16896 float4
        float4 z = {0.f, 0.f, 0.f, 0.f};
        for (int i = (b - 12800) * 256 + threadIdx.x; i < nvec; i += 16 * 256)
            ((float4*)zeroDst)[i] = z;
        return;
    }
    const float* src; short* dh; short* dl; int boff;
    if (b < 12288) {
        const int s = b >> 12;
        src = (s == 0) ? q  : (s == 1) ? k  : v;
        dh  = (s == 0) ? qh : (s == 1) ? kh : vh;
        dl  = (s == 0) ? ql : (s == 1) ? kl : vl;
        boff = b & 4095;
    } else {
        const int s = (b - 12288) >> 7;
        src = (s == 0) ? wq  : (s == 1) ? wk  : (s == 2) ? wv  : wm;
        dh  = (s == 0) ? wqh : (s == 1) ? wkh : (s == 2) ? wvh : wmh;
        dl  = (s == 0) ? wql : (s == 1) ? wkl : (s == 2) ? wvl : wml;
        boff = (b - 12288) & 127;
    }
    const size_t i = ((size_t)boff * 256 + threadIdx.x) * 8;
    float4 x0 = *(const float4*)(src + i);
    float4 x1 = *(const float4*)(src + i + 4);
    float vv[8] = {x0.x, x0.y, x0.z, x0.w, x1.x, x1.y, x1.z, x1.w};
    short8 h, l;
#pragma unroll
    for (int t = 0; t < 8; ++t) {
        short hb = f2bf(vv[t]);
        h[t] = hb;
        l[t] = f2bf(vv[t] - bf2f(hb));
    }
    *(short8*)(dh + i) = h;
    *(short8*)(dl + i) = l;
}

// ---- round-1 proven GEMM core: glds staging, linear LDS + XOR pair -------
// 128x128 tile, 4 waves 2x2, A AND B staged via global_load_lds from
// pre-split bf16 planes. Linear LDS [4][128][32] + XOR chunk swizzle
// (source chunk ^ (lane>>3)&3, read chunk kg ^ (l15>>1)&3) -> 2-way banked
// ds_read_b128 (free). Single buffer, 2 barriers/K-step; (256,3) => ~3
// blocks/CU hides the vmcnt drain. Measured 83 us / MfmaUtil 40 / 0 confl.
__device__ __forceinline__ void gemm_core_r1(
    const short* __restrict__ Ah, const short* __restrict__ Al,
    const short* __restrict__ Bh, const short* __restrict__ Bl,
    int bm, int bn, short (*lds)[128][32], f32x4 acc[4][4])
{
    const int tid  = threadIdx.x;
    const int lane = tid & 63;
    const int wave = tid >> 6;
    const int wm   = (wave >> 1) * 64;
    const int wn   = (wave & 1) * 64;
    const int l15  = lane & 15;
    const int kg   = lane >> 4;

    const int sr = lane >> 2;
    const int sc = (((lane & 3) ^ ((lane >> 3) & 3)) << 3);
    const int rt = wave * 32 + sr;
    const short* gAh = Ah + (size_t)(bm + rt) * EMBED + sc;
    const short* gAl = Al + (size_t)(bm + rt) * EMBED + sc;
    const short* gBh = Bh + (size_t)(bn + rt) * EMBED + sc;
    const short* gBl = Bl + (size_t)(bn + rt) * EMBED + sc;

    short* dAh = &lds[0][wave * 32][0];
    short* dAl = &lds[1][wave * 32][0];
    short* dBh = &lds[2][wave * 32][0];
    short* dBl = &lds[3][wave * 32][0];

    const int rk = ((kg ^ ((l15 >> 1) & 3)) << 3);

#pragma unroll 1
    for (int k0 = 0; k0 < EMBED; k0 += 32) {
        GLDS16(gAh + k0,              dAh);
        GLDS16(gAh + 16 * EMBED + k0, dAh + 512);
        GLDS16(gAl + k0,              dAl);
        GLDS16(gAl + 16 * EMBED + k0, dAl + 512);
        GLDS16(gBh + k0,              dBh);
        GLDS16(gBh + 16 * EMBED + k0, dBh + 512);
        GLDS16(gBl + k0,              dBl);
        GLDS16(gBl + 16 * EMBED + k0, dBl + 512);
        __syncthreads();                         // vmcnt(0) drain -> tile ready

        short8 ahv[4], alv[4], bhv[4], blv[4];
#pragma unroll
        for (int i = 0; i < 4; ++i) {
            ahv[i] = *(const short8*)&lds[0][wm + i * 16 + l15][rk];
            alv[i] = *(const short8*)&lds[1][wm + i * 16 + l15][rk];
            bhv[i] = *(const short8*)&lds[2][wn + i * 16 + l15][rk];
            blv[i] = *(const short8*)&lds[3][wn + i * 16 + l15][rk];
        }
#pragma unroll
        for (int i = 0; i < 4; ++i)
#pragma unroll
            for (int j = 0; j < 4; ++j) {
                acc[i][j] = __builtin_amdgcn_mfma_f32_16x16x32_bf16(ahv[i], bhv[j], acc[i][j], 0, 0, 0);
                acc[i][j] = __builtin_amdgcn_mfma_f32_16x16x32_bf16(ahv[i], blv[j], acc[i][j], 0, 0, 0);
                acc[i][j] = __builtin_amdgcn_mfma_f32_16x16x32_bf16(alv[i], bhv[j], acc[i][j], 0, 0, 0);
            }
        __syncthreads();                         // readers done before next stage
    }
}

// ---- fused QKV projection GEMM: Q->fp32, K/V->split bf16 planes ----------
__global__ __launch_bounds__(256, 3)
void qkv_gemm(const short* __restrict__ Aqh, const short* __restrict__ Aql,
              const short* __restrict__ Akh, const short* __restrict__ Akl,
              const short* __restrict__ Avh, const short* __restrict__ Avl,
              const short* __restrict__ WqH, const short* __restrict__ WqL,
              const short* __restrict__ WkH, const short* __restrict__ WkL,
              const short* __restrict__ WvH, const short* __restrict__ WvL,
              float* __restrict__ Qb,
              short* __restrict__ KhP, short* __restrict__ KlP,
              short* __restrict__ VhP, short* __restrict__ VlP) {
    __shared__ short lds[4][128][32];   // 32 KiB

    const int lin = blockIdx.x;
    const int op  = lin >> 9;                    // 0=q,1=k,2=v
    const int r_  = lin & 511;
    const int bn  = (r_ >> 7) * 128;             // y-major swizzle (L2/XCD)
    const int bm  = (r_ & 127) * 128;

    const short* Ah = (op == 0) ? Aqh : (op == 1) ? Akh : Avh;
    const short* Al = (op == 0) ? Aql : (op == 1) ? Akl : Avl;
    const short* Bh = (op == 0) ? WqH : (op == 1) ? WkH : WvH;
    const short* Bl = (op == 0) ? WqL : (op == 1) ? WkL : WvL;

    f32x4 acc[4][4];
#pragma unroll
    for (int i = 0; i < 4; ++i)
#pragma unroll
        for (int j = 0; j < 4; ++j) acc[i][j] = (f32x4)0.0f;

    gemm_core_r1(Ah, Al, Bh, Bl, bm, bn, lds, acc);

    const int lane = threadIdx.x & 63;
    const int wave = threadIdx.x >> 6;
    const int l15  = lane & 15;
    const int kg   = lane >> 4;
    const int wm   = (wave >> 1) * 64;
    const int wn   = (wave & 1) * 64;

    if (op == 0) {                       // Q: elu+1, fp32 (message needs it)
#pragma unroll
        for (int i = 0; i < 4; ++i)
#pragma unroll
            for (int j = 0; j < 4; ++j) {
                const int col = bn + wn + j * 16 + l15;
#pragma unroll
                for (int rr = 0; rr < 4; ++rr) {
                    const int row = bm + wm + i * 16 + kg * 4 + rr;
                    float vv = acc[i][j][rr];
                    vv = (vv > 0.f) ? (vv + 1.f) : __expf(vv);
                    Qb[(size_t)row * EMBED + col] = vv;
                }
            }
    } else {                             // K: elu+1; V: /SEQ; split bf16 out
        short* Hp = (op == 1) ? KhP : VhP;
        short* Lp = (op == 1) ? KlP : VlP;
#pragma unroll
        for (int i = 0; i < 4; ++i)
#pragma unroll
            for (int j = 0; j < 4; ++j) {
                const int col = bn + wn + j * 16 + l15;
#pragma unroll
                for (int rr = 0; rr < 4; ++rr) {
                    const int row = bm + wm + i * 16 + kg * 4 + rr;
                    float vv = acc[i][j][rr];
                    if (op == 1) vv = (vv > 0.f) ? (vv + 1.f) : __expf(vv);
                    else         vv = vv * (1.0f / (float)SEQ);
                    short hb = f2bf(vv);
                    Hp[(size_t)row * EMBED + col] = hb;
                    Lp[(size_t)row * EMBED + col] = f2bf(vv - bf2f(hb));
                }
            }
    }
}

// ---- merge GEMM: same core, plain fp32 store -----------------------------
__global__ __launch_bounds__(256, 3)
void merge_gemm(const short* __restrict__ Mh, const short* __restrict__ Ml,
                const short* __restrict__ WhP, const short* __restrict__ WlP,
                float* __restrict__ C) {
    __shared__ short lds[4][128][32];

    const int lin = blockIdx.x;
    const int bn  = (lin >> 7) * 128;
    const int bm  = (lin & 127) * 128;

    f32x4 acc[4][4];
#pragma unroll
    for (int i = 0; i < 4; ++i)
#pragma unroll
        for (int j = 0; j < 4; ++j) acc[i][j] = (f32x4)0.0f;

    gemm_core_r1(Mh, Ml, WhP, WlP, bm, bn, lds, acc);

    const int lane = threadIdx.x & 63;
    const int wave = threadIdx.x >> 6;
    const int l15  = lane & 15;
    const int kg   = lane >> 4;
    const int wm   = (wave >> 1) * 64;
    const int wn   = (wave & 1) * 64;
#pragma unroll
    for (int i = 0; i < 4; ++i)
#pragma unroll
        for (int j = 0; j < 4; ++j) {
            const int col = bn + wn + j * 16 + l15;
#pragma unroll
            for (int rr = 0; rr < 4; ++rr) {
                const int row = bm + wm + i * 16 + kg * 4 + rr;
                C[(size_t)row * EMBED + col] = acc[i][j][rr];
            }
        }
}

// ---- KV + Ksum MFMA: pre-split plane inputs, 8-chunk walk, 4-way atomics -
__global__ __launch_bounds__(256)
void kv_ksum_mfma(const short* __restrict__ KhP, const short* __restrict__ KlP,
                  const short* __restrict__ VhP, const short* __restrict__ VlP,
                  float* __restrict__ KV, float* __restrict__ Ksum) {
    __shared__ char smem[34816];
    short (*Kh)[34] = (short (*)[34])smem;
    short (*Kl)[34] = (short (*)[34])(smem + 8704);
    short (*Vh)[34] = (short (*)[34])(smem + 17408);
    short (*Vl)[34] = (short (*)[34])(smem + 26112);

    const int bh_ = blockIdx.y;
    const int b = bh_ >> 4, h = bh_ & 15;
    const int s0 = blockIdx.x * 1024;           // 4 blocks x 1024 rows each
    const int t = threadIdx.x;
    const int lane = t & 63, wave = t >> 6;
    const int l15 = lane & 15, kg = lane >> 4;
    const int ws = wave * 32;

    const int sl = t >> 1;
    const int dsel = (t & 1) * 16;
    const size_t rbase = (size_t)(b * SEQ + s0 + sl) * EMBED + h * HDIM + dsel;

    f32x4 kvacc[2][2], ksacc[2];
#pragma unroll
    for (int i = 0; i < 2; ++i) {
        ksacc[i] = (f32x4)0.0f;
#pragma unroll
        for (int j = 0; j < 2; ++j) kvacc[i][j] = (f32x4)0.0f;
    }
    short8 ones;
#pragma unroll
    for (int q = 0; q < 8; ++q) ones[q] = (short)0x3F80;   // bf16 1.0

    short8 pk[4], pv[4];   // {kh0,kh1,kl0,kl1}, {vh0,vh1,vl0,vl1}
    pk[0] = *(const short8*)(KhP + rbase);
    pk[1] = *(const short8*)(KhP + rbase + 8);
    pk[2] = *(const short8*)(KlP + rbase);
    pk[3] = *(const short8*)(KlP + rbase + 8);
    pv[0] = *(const short8*)(VhP + rbase);
    pv[1] = *(const short8*)(VhP + rbase + 8);
    pv[2] = *(const short8*)(VlP + rbase);
    pv[3] = *(const short8*)(VlP + rbase + 8);

#pragma unroll 1
    for (int it = 0; it < 8; ++it) {
        __syncthreads();
        *(short8*)&Kh[sl][dsel]     = pk[0];
        *(short8*)&Kh[sl][dsel + 8] = pk[1];
        *(short8*)&Kl[sl][dsel]     = pk[2];
        *(short8*)&Kl[sl][dsel + 8] = pk[3];
        *(short8*)&Vh[sl][dsel]     = pv[0];
        *(short8*)&Vh[sl][dsel + 8] = pv[1];
        *(short8*)&Vl[sl][dsel]     = pv[2];
        *(short8*)&Vl[sl][dsel + 8] = pv[3];
        __syncthreads();
        if (it < 7) {
            const size_t rb2 = rbase + (size_t)(it + 1) * 128 * EMBED;
            pk[0] = *(const short8*)(KhP + rb2);
            pk[1] = *(const short8*)(KhP + rb2 + 8);
            pk[2] = *(const short8*)(KlP + rb2);
            pk[3] = *(const short8*)(KlP + rb2 + 8);
            pv[0] = *(const short8*)(VhP + rb2);
            pv[1] = *(const short8*)(VhP + rb2 + 8);
            pv[2] = *(const short8*)(VlP + rb2);
            pv[3] = *(const short8*)(VlP + rb2 + 8);
        }
        short8 kah[2], kal[2], vbh[2], vbl[2];
#pragma unroll
        for (int i = 0; i < 2; ++i) {
#pragma unroll
            for (int q = 0; q < 8; ++q) {
                const int srow = ws + kg * 8 + q;
                const int col  = i * 16 + l15;
                kah[i][q] = Kh[srow][col];
                kal[i][q] = Kl[srow][col];
                vbh[i][q] = Vh[srow][col];
                vbl[i][q] = Vl[srow][col];
            }
        }
#pragma unroll
        for (int i = 0; i < 2; ++i) {
#pragma unroll
            for (int j = 0; j < 2; ++j) {
                kvacc[i][j] = __builtin_amdgcn_mfma_f32_16x16x32_bf16(kah[i], vbh[j], kvacc[i][j], 0, 0, 0);
                kvacc[i][j] = __builtin_amdgcn_mfma_f32_16x16x32_bf16(kah[i], vbl[j], kvacc[i][j], 0, 0, 0);
                kvacc[i][j] = __builtin_amdgcn_mfma_f32_16x16x32_bf16(kal[i], vbh[j], kvacc[i][j], 0, 0, 0);
            }
            ksacc[i] = __builtin_amdgcn_mfma_f32_16x16x32_bf16(kah[i], ones, ksacc[i], 0, 0, 0);
            ksacc[i] = __builtin_amdgcn_mfma_f32_16x16x32_bf16(kal[i], ones, ksacc[i], 0, 0, 0);
        }
    }

    __syncthreads();
    float* red = (float*)smem;
    float* myred = red + wave * 1056;
#pragma unroll
    for (int i = 0; i < 2; ++i)
#pragma unroll
        for (int j = 0; j < 2; ++j)
#pragma unroll
            for (int r = 0; r < 4; ++r)
                myred[(i * 16 + kg * 4 + r) * 32 + j * 16 + l15] = kvacc[i][j][r];
    if (l15 == 0) {
#pragma unroll
        for (int i = 0; i < 2; ++i)
#pragma unroll
            for (int r = 0; r < 4; ++r)
                myred[1024 + i * 16 + kg * 4 + r] = ksacc[i][r];
    }
    __syncthreads();
    float* kvout = KV + (size_t)bh_ * 1024;
    for (int idx = t; idx < 1024; idx += 256) {
        float s4 = red[idx] + red[1056 + idx] + red[2112 + idx] + red[3168 + idx];
        atomicAdd(&kvout[idx], s4);
    }
    if (t < 32) {
        float s4 = red[1024 + t] + red[1056 + 1024 + t] + red[2112 + 1024 + t] + red[3168 + 1024 + t];
        atomicAdd(&Ksum[bh_ * 32 + t], s4);
    }
}

// ---- message: M[l,h,:] = (SEQ/(Q.Ksum+eps)) * Q @ KV[b,h], emit split bf16
__global__ __launch_bounds__(512)
void message_kernel(const float* __restrict__ Q, const float* __restrict__ KV,
                    const float* __restrict__ Ksum,
                    short* __restrict__ Mh, short* __restrict__ Ml) {
    const int blk  = blockIdx.x;
    const int row0 = blk * 4;
    const int b    = row0 >> 12;
    const int t    = threadIdx.x;
    const int h    = t >> 5, e = t & 31;

    __shared__ float q[4][EMBED];
    __shared__ float ks[EMBED];
    ks[t] = Ksum[b * EMBED + t];
#pragma unroll
    for (int r = 0; r < 4; ++r) q[r][t] = Q[(size_t)(row0 + r) * EMBED + t];

    const float* kvh = KV + (size_t)(b * NHEAD + h) * HDIM * HDIM + e;
    float kc[HDIM];
#pragma unroll
    for (int d = 0; d < HDIM; ++d) kc[d] = kvh[d * HDIM];
    __syncthreads();

#pragma unroll
    for (int r = 0; r < 4; ++r) {
        float zden = FEPS, m = 0.f;
#pragma unroll
        for (int d = 0; d < HDIM; ++d) {
            float qd = q[r][h * HDIM + d];
            zden = fmaf(qd, ks[h * HDIM + d], zden);
            m    = fmaf(qd, kc[d], m);
        }
        float vv = m * ((float)SEQ / zden);
        short hb = f2bf(vv);
        Mh[(size_t)(row0 + r) * EMBED + t] = hb;
        Ml[(size_t)(row0 + r) * EMBED + t] = f2bf(vv - bf2f(hb));
    }
}

// ---- launch ----
extern "C" void kernel_launch(void* const* d_in, const int* in_sizes, int n_in,
                              void* d_out, int out_size, void* d_ws, size_t ws_size,
                              hipStream_t stream) {
    const float* query = (const float*)d_in[0];
    const float* key   = (const float*)d_in[1];
    const float* value = (const float*)d_in[2];
    const float* Wq    = (const float*)d_in[3];
    const float* Wk    = (const float*)d_in[4];
    const float* Wv    = (const float*)d_in[5];
    const float* Wm    = (const float*)d_in[6];
    float* out = (float*)d_out;

    float* ws  = (float*)d_ws;
    float* Qb  = ws;                              // NE fp32
    short* KhP = (short*)(Qb + (size_t)NE);       // 4 split K/V planes, NE each
    short* KlP = KhP + (size_t)NE;
    short* VhP = KhP + 2 * (size_t)NE;
    short* VlP = KhP + 3 * (size_t)NE;
    float* KVb = (float*)(KhP + 4 * (size_t)NE);  // 64*1024
    float* KSb = KVb + 64 * 1024;                 // 64*32
    short* wsp = (short*)(KSb + 64 * HDIM);
    short* WqH = wsp;            short* WqL = wsp + WN;
    short* WkH = wsp + 2 * WN;   short* WkL = wsp + 3 * WN;
    short* WvH = wsp + 4 * WN;   short* WvL = wsp + 5 * WN;
    short* WmH = wsp + 6 * WN;   short* WmL = wsp + 7 * WN;
    short* Xp  = wsp + 8 * WN;                    // 6 input planes, NE shorts each
    short* Qih = Xp;             short* Qil = Xp + (size_t)NE;
    short* Kih = Xp + 2 * (size_t)NE;  short* Kil = Xp + 3 * (size_t)NE;
    short* Vih = Xp + 4 * (size_t)NE;  short* Vil = Xp + 5 * (size_t)NE;
    // message planes alias Kih/Kil (dead after qkv_gemm)
    short* Mh = Kih;
    short* Ml = Kil;

    convert_all<<<12816, 256, 0, stream>>>(query, key, value, Wq, Wk, Wv, Wm,
                                           Qih, Qil, Kih, Kil, Vih, Vil,
                                           WqH, WqL, WkH, WkL,
                                           WvH, WvL, WmH, WmL, KVb);

    qkv_gemm<<<1536, 256, 0, stream>>>(Qih, Qil, Kih, Kil, Vih, Vil,
                                       WqH, WqL, WkH, WkL, WvH, WvL,
                                       Qb, KhP, KlP, VhP, VlP);

    kv_ksum_mfma<<<dim3(4, 64), 256, 0, stream>>>(KhP, KlP, VhP, VlP, KVb, KSb);
    message_kernel<<<NROWS / 4, 512, 0, stream>>>(Qb, KVb, KSb, Mh, Ml);

    merge_gemm<<<512, 256, 0, stream>>>(Mh, Ml, WmH, WmL, out);
}